// Round 1
// baseline (169.217 us; speedup 1.0000x reference)
//
#include <hip/hip_runtime.h>

// RoPE sin/cos table gather:
//   out[pos_idx, 2k]   = cache[p, k, 1]  (cos)
//   out[pos_idx, 2k+1] = cache[p, k, 0]  (sin)
// cache row is contiguous 512 floats: [sin0, cos0, sin1, cos1, ...]
// -> per-float4 pairwise swap, fully coalesced 16B/lane loads and stores.

#define EMBED_DIM 512
#define VEC_PER_POS (EMBED_DIM / 4)   // 128 float4 per position row

__global__ __launch_bounds__(256) void ScalarRoPEEmbedding_83769042141635_kernel(
    const int* __restrict__ positions,
    const float* __restrict__ cache,
    float* __restrict__ out,
    int n_pos)
{
    int tid = blockIdx.x * blockDim.x + threadIdx.x;
    int pos_idx = tid >> 7;        // tid / 128
    int lane    = tid & 127;       // tid % 128
    if (pos_idx >= n_pos) return;

    int p = positions[pos_idx];    // wave-uniform per 128-thread group -> broadcast

    const float4* __restrict__ src =
        (const float4*)(cache + (size_t)p * EMBED_DIM);
    float4 v = src[lane];
    // (sin0, cos0, sin1, cos1) -> (cos0, sin0, cos1, sin1)
    float4 w = make_float4(v.y, v.x, v.w, v.z);

    float4* __restrict__ dst = (float4*)(out + (size_t)pos_idx * EMBED_DIM);
    dst[lane] = w;
}

extern "C" void kernel_launch(void* const* d_in, const int* in_sizes, int n_in,
                              void* d_out, int out_size, void* d_ws, size_t ws_size,
                              hipStream_t stream) {
    const int*   positions = (const int*)d_in[0];
    const float* cache     = (const float*)d_in[1];
    float*       out       = (float*)d_out;

    int n_pos = in_sizes[0];                      // 8 * 8192 = 65536
    int total_threads = n_pos * VEC_PER_POS;      // 128 threads per position
    int block = 256;
    int grid = (total_threads + block - 1) / block;

    ScalarRoPEEmbedding_83769042141635_kernel<<<grid, block, 0, stream>>>(
        positions, cache, out, n_pos);
}

// Round 3
// 160.999 us; speedup vs baseline: 1.0510x; 1.0510x over previous
//
#include <hip/hip_runtime.h>

// RoPE sin/cos table gather:
//   out[pos_idx, 2k]   = cache[p, k, 1]  (cos)
//   out[pos_idx, 2k+1] = cache[p, k, 0]  (sin)
// cache row is contiguous 512 floats: [sin0, cos0, sin1, cos1, ...]
// -> per-float4 pairwise swap, fully coalesced 16B/lane loads and stores.
//
// 32 threads per position, 4 float4 per thread (MLP=4, independent loads).
// Non-temporal stores keep the 20 MiB table resident in L2 while the
// 128 MiB output streams past it.
//
// NOTE: __builtin_nontemporal_store requires a NATIVE vector type, not
// HIP_vector_type<float,4> — use ext_vector_type(4).

#define EMBED_DIM 512
#define THREADS_PER_POS 32           // 32 threads x 4 float4 = 128 float4 = 512 floats

typedef float v4f __attribute__((ext_vector_type(4)));

__global__ __launch_bounds__(256) void ScalarRoPEEmbedding_83769042141635_kernel(
    const int* __restrict__ positions,
    const float* __restrict__ cache,
    float* __restrict__ out,
    int n_pos)
{
    int tid = blockIdx.x * blockDim.x + threadIdx.x;
    int pos_idx = tid >> 5;        // tid / 32
    int sub     = tid & 31;        // tid % 32
    if (pos_idx >= n_pos) return;

    int p = positions[pos_idx];    // uniform per 32-thread group -> broadcast

    const v4f* __restrict__ src = (const v4f*)(cache + (size_t)p * EMBED_DIM);
    v4f* __restrict__ dst       = (v4f*)(out + (size_t)pos_idx * EMBED_DIM);

    // 4 independent loads in flight, then 4 stores.
    v4f v0 = src[sub];
    v4f v1 = src[sub + 32];
    v4f v2 = src[sub + 64];
    v4f v3 = src[sub + 96];

    // (sin0, cos0, sin1, cos1) -> (cos0, sin0, cos1, sin1)
    v4f w0 = {v0.y, v0.x, v0.w, v0.z};
    v4f w1 = {v1.y, v1.x, v1.w, v1.z};
    v4f w2 = {v2.y, v2.x, v2.w, v2.z};
    v4f w3 = {v3.y, v3.x, v3.w, v3.z};

    __builtin_nontemporal_store(w0, &dst[sub]);
    __builtin_nontemporal_store(w1, &dst[sub + 32]);
    __builtin_nontemporal_store(w2, &dst[sub + 64]);
    __builtin_nontemporal_store(w3, &dst[sub + 96]);
}

extern "C" void kernel_launch(void* const* d_in, const int* in_sizes, int n_in,
                              void* d_out, int out_size, void* d_ws, size_t ws_size,
                              hipStream_t stream) {
    const int*   positions = (const int*)d_in[0];
    const float* cache     = (const float*)d_in[1];
    float*       out       = (float*)d_out;

    int n_pos = in_sizes[0];                       // 8 * 8192 = 65536
    int total_threads = n_pos * THREADS_PER_POS;   // 2.1M threads
    int block = 256;
    int grid = (total_threads + block - 1) / block;

    ScalarRoPEEmbedding_83769042141635_kernel<<<grid, block, 0, stream>>>(
        positions, cache, out, n_pos);
}